// Round 1
// baseline (53588.806 us; speedup 1.0000x reference)
//
#include <hip/hip_runtime.h>
#include <hip/hip_bf16.h>

#define S 1024
#define D 1024
#define DI 2048
#define NSTATE 16
#define DTR 64
#define XPD 96      // DT_RANK + 2N
#define NL 48
#define CARD 2048
#define KTOK 4

typedef __attribute__((ext_vector_type(8))) short bf16x8;
typedef __attribute__((ext_vector_type(4))) float f32x4;

__device__ __forceinline__ unsigned short f2bf(float f) {
    unsigned u = __builtin_bit_cast(unsigned, f);
    return (unsigned short)((u + 0x7fffu + ((u >> 16) & 1u)) >> 16);
}
__device__ __forceinline__ float fsilu(float x) { return x / (1.f + __expf(-x)); }
__device__ __forceinline__ float fsoftplus(float x) {
    return fmaxf(x, 0.f) + log1pf(__expf(-fabsf(x)));
}

// ---------------- embedding: x[s][d] = sum_k emb_W[k][seq[k][s]][d] ----------------
__global__ __launch_bounds__(256) void embed_kernel(const int* __restrict__ seq,
                                                    const float* __restrict__ embW,
                                                    float* __restrict__ x) {
    int s = blockIdx.x, t = threadIdx.x;
    f32x4 acc = (f32x4)0.f;
#pragma unroll
    for (int k = 0; k < KTOK; ++k) {
        int tok = seq[k * S + s];
        const f32x4 v = *(const f32x4*)&embW[((size_t)k * CARD + tok) * D + t * 4];
        acc += v;
    }
    *(f32x4*)&x[(size_t)s * D + t * 4] = acc;
}

// ---------------- RMSNorm over rows of length D ----------------
__global__ __launch_bounds__(256) void rmsnorm_kernel(const float* __restrict__ x,
                                                      const float* __restrict__ w,
                                                      float* __restrict__ o) {
    int row = blockIdx.x, t = threadIdx.x;
    f32x4 v = *(const f32x4*)&x[(size_t)row * D + t * 4];
    float ss = v[0]*v[0] + v[1]*v[1] + v[2]*v[2] + v[3]*v[3];
#pragma unroll
    for (int off = 32; off >= 1; off >>= 1) ss += __shfl_xor(ss, off);
    __shared__ float red[4];
    int wave = t >> 6, lane = t & 63;
    if (lane == 0) red[wave] = ss;
    __syncthreads();
    ss = red[0] + red[1] + red[2] + red[3];
    float rs = rsqrtf(ss * (1.f / D) + 1e-5f);
    f32x4 wv = *(const f32x4*)&w[t * 4];
    f32x4 ov;
#pragma unroll
    for (int j = 0; j < 4; ++j) ov[j] = v[j] * rs * wv[j];
    *(f32x4*)&o[(size_t)row * D + t * 4] = ov;
}

// ---------------- causal depthwise conv1d (k=4) + bias + silu ----------------
__global__ __launch_bounds__(256) void conv_silu_kernel(const float* __restrict__ proj,
                                                        const float* __restrict__ cw,
                                                        const float* __restrict__ cb,
                                                        float* __restrict__ u) {
    int idx = blockIdx.x * 256 + threadIdx.x;   // s*DI + c
    int s = idx >> 11, c = idx & (DI - 1);
    f32x4 w = *(const f32x4*)&cw[c * 4];
    float acc = cb[c];
#pragma unroll
    for (int t = 0; t < 4; ++t) {
        int ss = s - 3 + t;
        if (ss >= 0) acc = fmaf(w[t], proj[(size_t)ss * 4096 + c], acc);
    }
    u[idx] = acc * (1.f / (1.f + __expf(-acc)));   // silu
}

// ---------------- selective scan: thread = (channel d, state n) ----------------
__global__ __launch_bounds__(256) void scan_kernel(const float* __restrict__ dt,
                                                   const float* __restrict__ u,
                                                   const float* __restrict__ ssm,
                                                   const float* __restrict__ proj,
                                                   const float* __restrict__ A_log,
                                                   const float* __restrict__ Dsk,
                                                   float* __restrict__ yf) {
    int idx = blockIdx.x * 256 + threadIdx.x;   // d*16 + n
    int d = idx >> 4, n = idx & 15;
    float A = -__expf(A_log[idx]);              // A_log is (DI,16) contiguous
    float Dv = Dsk[d];
    float h = 0.f;
#pragma unroll 4
    for (int s = 0; s < S; ++s) {
        float dts = dt[(size_t)s * DI + d];
        float us  = u[(size_t)s * DI + d];
        float Bs  = ssm[s * XPD + DTR + n];
        float Cs  = ssm[s * XPD + DTR + NSTATE + n];
        float dA  = __expf(dts * A);
        h = fmaf(dA, h, dts * us * Bs);
        float pc = h * Cs;
        pc += __shfl_xor(pc, 1);
        pc += __shfl_xor(pc, 2);
        pc += __shfl_xor(pc, 4);
        pc += __shfl_xor(pc, 8);
        float g = proj[(size_t)s * 4096 + 2048 + d];   // gate
        if (n == 0)
            yf[(size_t)s * DI + d] = (pc + us * Dv) * fsilu(g);
    }
}

// ---------------- GEMM: C(1024 x N) = A(1024 x K, lda) * W(N x K)^T ----------------
// bf16 MFMA 16x16x32, 128 x (NR*32) tile, 4 waves (2x2), reg-staged fp32->bf16.
// EPI: 0 none, 1 softplus(acc+bias), 2 acc+res (residual), 3 acc+bias with z-batch (head)
template<int NR, int EPI>
__global__ __launch_bounds__(256) void gemm_bt(const float* __restrict__ A, int lda,
                                               const float* __restrict__ W,
                                               float* __restrict__ C,
                                               int K, int N,
                                               const float* __restrict__ bias,
                                               const float* __restrict__ res) {
    constexpr int BN = NR * 32;
    __shared__ unsigned short As[128][32];
    __shared__ unsigned short Ws[BN][32];
    const int tid = threadIdx.x;
    const int lane = tid & 63;
    const int wave = tid >> 6;
    const int wr = wave >> 1, wc = wave & 1;
    const int m0 = blockIdx.y * 128;
    const int n0 = blockIdx.x * BN;
    if (EPI == 3) {
        size_t z = blockIdx.z;
        W += z * (size_t)N * K;
        C += z * (size_t)1024 * N;
        bias += z * N;
    }
    f32x4 acc[4][NR];
#pragma unroll
    for (int m = 0; m < 4; ++m)
#pragma unroll
        for (int n = 0; n < NR; ++n) acc[m][n] = (f32x4)0.f;

    const int lr = lane & 15;            // fragment row/col within 16
    const int lk = (lane >> 4) << 3;     // k-offset (8 bf16 per lane-group)

    for (int k0 = 0; k0 < K; k0 += 32) {
        __syncthreads();
#pragma unroll
        for (int i = 0; i < 4; ++i) {    // stage A: 128x32
            int idx = tid + i * 256;
            int row = idx >> 3, c4 = (idx & 7) << 2;
            f32x4 v = *(const f32x4*)&A[(size_t)(m0 + row) * lda + k0 + c4];
            unsigned long long pk = (unsigned long long)f2bf(v[0])
                                  | ((unsigned long long)f2bf(v[1]) << 16)
                                  | ((unsigned long long)f2bf(v[2]) << 32)
                                  | ((unsigned long long)f2bf(v[3]) << 48);
            *(unsigned long long*)&As[row][c4] = pk;
        }
#pragma unroll
        for (int i = 0; i < NR; ++i) {   // stage W: BN x 32
            int idx = tid + i * 256;
            int row = idx >> 3, c4 = (idx & 7) << 2;
            f32x4 v = *(const f32x4*)&W[(size_t)(n0 + row) * K + k0 + c4];
            unsigned long long pk = (unsigned long long)f2bf(v[0])
                                  | ((unsigned long long)f2bf(v[1]) << 16)
                                  | ((unsigned long long)f2bf(v[2]) << 32)
                                  | ((unsigned long long)f2bf(v[3]) << 48);
            *(unsigned long long*)&Ws[row][c4] = pk;
        }
        __syncthreads();
        bf16x8 af[4], wf[NR];
#pragma unroll
        for (int m = 0; m < 4; ++m)
            af[m] = *(const bf16x8*)&As[wr * 64 + m * 16 + lr][lk];
#pragma unroll
        for (int n = 0; n < NR; ++n)
            wf[n] = *(const bf16x8*)&Ws[wc * (NR * 16) + n * 16 + lr][lk];
#pragma unroll
        for (int m = 0; m < 4; ++m)
#pragma unroll
            for (int n = 0; n < NR; ++n)
                acc[m][n] = __builtin_amdgcn_mfma_f32_16x16x32_bf16(af[m], wf[n], acc[m][n], 0, 0, 0);
    }

    const int mo = m0 + wr * 64;
    const int no = n0 + wc * (NR * 16);
    const int rbase = (lane >> 4) << 2;
#pragma unroll
    for (int m = 0; m < 4; ++m) {
#pragma unroll
        for (int n = 0; n < NR; ++n) {
            int col = no + n * 16 + lr;
#pragma unroll
            for (int j = 0; j < 4; ++j) {
                int row = mo + m * 16 + rbase + j;
                float v = acc[m][n][j];
                if (EPI == 1) v = fsoftplus(v + bias[col]);
                else if (EPI == 2) v += res[(size_t)row * N + col];
                else if (EPI == 3) v += bias[col];
                C[(size_t)row * N + col] = v;
            }
        }
    }
}

extern "C" void kernel_launch(void* const* d_in, const int* in_sizes, int n_in,
                              void* d_out, int out_size, void* d_ws, size_t ws_size,
                              hipStream_t stream) {
    const int*   seq     = (const int*)d_in[0];
    const float* embW    = (const float*)d_in[1];
    const float* norm_w  = (const float*)d_in[2];
    const float* in_W    = (const float*)d_in[3];
    const float* conv_w  = (const float*)d_in[4];
    const float* conv_b  = (const float*)d_in[5];
    const float* x_W     = (const float*)d_in[6];
    const float* dt_W    = (const float*)d_in[7];
    const float* dt_b    = (const float*)d_in[8];
    const float* A_log   = (const float*)d_in[9];
    const float* D_skip  = (const float*)d_in[10];
    const float* out_W   = (const float*)d_in[11];
    const float* normf_w = (const float*)d_in[12];
    const float* head_W  = (const float*)d_in[13];
    const float* head_b  = (const float*)d_in[14];

    float* ws   = (float*)d_ws;
    float* x    = ws;                         // S*D
    float* hn   = x    + (size_t)S * D;       // S*D
    float* proj = hn   + (size_t)S * D;       // S*4096
    float* u    = proj + (size_t)S * 4096;    // S*DI
    float* ssm  = u    + (size_t)S * DI;      // S*96 (pad to 128)
    float* dtv  = ssm  + (size_t)S * 128;     // S*DI
    float* yf   = dtv  + (size_t)S * DI;      // S*DI

    embed_kernel<<<S, 256, 0, stream>>>(seq, embW, x);

    for (int l = 0; l < NL; ++l) {
        rmsnorm_kernel<<<S, 256, 0, stream>>>(x, norm_w + (size_t)l * D, hn);
        gemm_bt<4, 0><<<dim3(32, 8), 256, 0, stream>>>(hn, D, in_W + (size_t)l * 4096 * D,
                                                       proj, D, 4096, nullptr, nullptr);
        conv_silu_kernel<<<(S * DI) / 256, 256, 0, stream>>>(proj, conv_w + (size_t)l * DI * 4,
                                                             conv_b + (size_t)l * DI, u);
        gemm_bt<3, 0><<<dim3(1, 8), 256, 0, stream>>>(u, DI, x_W + (size_t)l * XPD * DI,
                                                      ssm, DI, XPD, nullptr, nullptr);
        gemm_bt<4, 1><<<dim3(16, 8), 256, 0, stream>>>(ssm, XPD, dt_W + (size_t)l * DI * DTR,
                                                       dtv, DTR, DI, dt_b + (size_t)l * DI, nullptr);
        scan_kernel<<<(DI * NSTATE) / 256, 256, 0, stream>>>(dtv, u, ssm, proj,
                                                             A_log + (size_t)l * DI * NSTATE,
                                                             D_skip + (size_t)l * DI, yf);
        gemm_bt<4, 2><<<dim3(8, 8), 256, 0, stream>>>(yf, DI, out_W + (size_t)l * D * DI,
                                                      x, DI, D, nullptr, x);
    }

    rmsnorm_kernel<<<S, 256, 0, stream>>>(x, normf_w, hn);
    gemm_bt<4, 3><<<dim3(16, 8, 4), 256, 0, stream>>>(hn, D, head_W, (float*)d_out,
                                                      D, CARD, head_b, nullptr);
}

// Round 2
// 10063.512 us; speedup vs baseline: 5.3251x; 5.3251x over previous
//
#include <hip/hip_runtime.h>
#include <hip/hip_bf16.h>

#define S 1024
#define D 1024
#define DI 2048
#define NSTATE 16
#define DTR 64
#define XPD 96      // DT_RANK + 2N
#define NL 48
#define CARD 2048
#define KTOK 4

typedef __attribute__((ext_vector_type(8))) short bf16x8;
typedef __attribute__((ext_vector_type(4))) float f32x4;

__device__ __forceinline__ unsigned short f2bf(float f) {
    unsigned u = __builtin_bit_cast(unsigned, f);
    return (unsigned short)((u + 0x7fffu + ((u >> 16) & 1u)) >> 16);
}
__device__ __forceinline__ float fsilu(float x) { return x / (1.f + __expf(-x)); }
__device__ __forceinline__ float fsoftplus(float x) {
    return fmaxf(x, 0.f) + log1pf(__expf(-fabsf(x)));
}

// ---------------- embedding: x[s][d] = sum_k emb_W[k][seq[k][s]][d] ----------------
__global__ __launch_bounds__(256) void embed_kernel(const int* __restrict__ seq,
                                                    const float* __restrict__ embW,
                                                    float* __restrict__ x) {
    int s = blockIdx.x, t = threadIdx.x;
    f32x4 acc = (f32x4)0.f;
#pragma unroll
    for (int k = 0; k < KTOK; ++k) {
        int tok = seq[k * S + s];
        const f32x4 v = *(const f32x4*)&embW[((size_t)k * CARD + tok) * D + t * 4];
        acc += v;
    }
    *(f32x4*)&x[(size_t)s * D + t * 4] = acc;
}

// ---------------- RMSNorm over rows of length D, bf16 output ----------------
__global__ __launch_bounds__(256) void rmsnorm_kernel(const float* __restrict__ x,
                                                      const float* __restrict__ w,
                                                      unsigned short* __restrict__ o) {
    int row = blockIdx.x, t = threadIdx.x;
    f32x4 v = *(const f32x4*)&x[(size_t)row * D + t * 4];
    float ss = v[0]*v[0] + v[1]*v[1] + v[2]*v[2] + v[3]*v[3];
#pragma unroll
    for (int off = 32; off >= 1; off >>= 1) ss += __shfl_xor(ss, off);
    __shared__ float red[4];
    int wave = t >> 6, lane = t & 63;
    if (lane == 0) red[wave] = ss;
    __syncthreads();
    ss = red[0] + red[1] + red[2] + red[3];
    float rs = rsqrtf(ss * (1.f / D) + 1e-5f);
    f32x4 wv = *(const f32x4*)&w[t * 4];
    unsigned long long pk = 0;
#pragma unroll
    for (int j = 0; j < 4; ++j)
        pk |= (unsigned long long)f2bf(v[j] * rs * wv[j]) << (16 * j);
    *(unsigned long long*)&o[(size_t)row * D + t * 4] = pk;
}

// ---------- causal depthwise conv1d (k=4) + bias + silu; also zeroes ssm ----------
__global__ __launch_bounds__(256) void conv_silu_kernel(const float* __restrict__ proj,
                                                        const float* __restrict__ cw,
                                                        const float* __restrict__ cb,
                                                        float* __restrict__ u,
                                                        unsigned short* __restrict__ ub,
                                                        float* __restrict__ ssm_zero) {
    int idx = blockIdx.x * 256 + threadIdx.x;   // s*DI + c
    if (blockIdx.x < (S * XPD) / 256)           // 384 blocks zero ssm (1024*96)
        ssm_zero[idx] = 0.f;
    int s = idx >> 11, c = idx & (DI - 1);
    f32x4 w = *(const f32x4*)&cw[c * 4];
    float acc = cb[c];
#pragma unroll
    for (int t = 0; t < 4; ++t) {
        int ss = s - 3 + t;
        if (ss >= 0) acc = fmaf(w[t], proj[(size_t)ss * 4096 + c], acc);
    }
    float r = acc * (1.f / (1.f + __expf(-acc)));   // silu
    u[idx] = r;
    ub[idx] = f2bf(r);
}

// ---------------- chunked selective scan (2-phase, fused) ----------------
// block: 1024 thr = 16 chunks x 4 d x 16 n; grid = DI/4 = 512 blocks.
// Pass A: per-chunk (P = prod dA, Q = local scan end). In-LDS combine gives each
// thread its chunk's h_init; pass B rescans with correct init, emits y (bf16).
__global__ __launch_bounds__(1024, 2) void scan2_kernel(const float* __restrict__ dt,
                                                        const float* __restrict__ u,
                                                        const float* __restrict__ ssm,
                                                        const float* __restrict__ proj,
                                                        const float* __restrict__ A_log,
                                                        const float* __restrict__ Dsk,
                                                        unsigned short* __restrict__ yfb) {
    __shared__ float sdt[S * 4];      // [s][dl]
    __shared__ float su[S * 4];
    __shared__ float sg[S * 4];       // gate in, y out (in-place after use)
    __shared__ float sP[1024], sQ[1024];

    const int tid = threadIdx.x;
    const int d0 = blockIdx.x * 4;
    const int chunk = tid >> 6;       // 16 chunks of 64 steps
    const int dl = (tid >> 4) & 3;
    const int n = tid & 15;

    // cooperative stage of dt, u, gate for the block's 4 channels
#pragma unroll
    for (int i = 0; i < 4; ++i) {
        int idx = tid + i * 1024;
        int s = idx >> 2, d2 = idx & 3;
        sdt[idx] = dt[(size_t)s * DI + d0 + d2];
        su[idx]  = u[(size_t)s * DI + d0 + d2];
        sg[idx]  = proj[(size_t)s * 4096 + 2048 + d0 + d2];
    }
    const float Av = -__expf(A_log[(d0 + dl) * NSTATE + n]);
    const float Dv = Dsk[d0 + dl];
    __syncthreads();

    const int sbase = chunk * 64;
    // pass A: local scan from zero + product of dA
    float h = 0.f, P = 1.f;
#pragma unroll 4
    for (int i = 0; i < 64; ++i) {
        int s = sbase + i;
        float dts = sdt[s * 4 + dl];
        float us  = su[s * 4 + dl];
        float Bs  = ssm[s * XPD + DTR + n];
        float dA  = __expf(dts * Av);
        P *= dA;
        h = fmaf(dA, h, dts * us * Bs);
    }
    const int pqb = (dl * 16 + n) * 16;
    sP[pqb + chunk] = P;
    sQ[pqb + chunk] = h;
    __syncthreads();
    // compose own h_init from earlier chunks
    float hi = 0.f;
    for (int j = 0; j < chunk; ++j) hi = fmaf(sP[pqb + j], hi, sQ[pqb + j]);
    // pass B: true scan + output
    h = hi;
#pragma unroll 4
    for (int i = 0; i < 64; ++i) {
        int s = sbase + i;
        float dts = sdt[s * 4 + dl];
        float us  = su[s * 4 + dl];
        float Bs  = ssm[s * XPD + DTR + n];
        float Cs  = ssm[s * XPD + DTR + NSTATE + n];
        float dA  = __expf(dts * Av);
        h = fmaf(dA, h, dts * us * Bs);
        float pc = h * Cs;
        pc += __shfl_xor(pc, 1);
        pc += __shfl_xor(pc, 2);
        pc += __shfl_xor(pc, 4);
        pc += __shfl_xor(pc, 8);
        if (n == 0) {
            float g = sg[s * 4 + dl];
            sg[s * 4 + dl] = (pc + us * Dv) * fsilu(g);
        }
    }
    __syncthreads();
#pragma unroll
    for (int i = 0; i < 4; ++i) {
        int idx = tid + i * 1024;
        int s = idx >> 2, d2 = idx & 3;
        yfb[(size_t)s * DI + d0 + d2] = f2bf(sg[idx]);
    }
}

// ---------------- GEMM: C(1024 x N) = A(1024 x K, lda) * W(N x K)^T ----------------
// bf16 MFMA 16x16x32, 128 x (NR*32) tile, 4 waves (2x2).
// EPI: 0 store, 1 softplus(acc+bias) store, 2 atomicAdd (split-K / residual), 3 bias+store z-batched
// ABF16: A is bf16 (direct 16B stage), else fp32 (reg-stage + convert)
template<int NR, int EPI, int KSPLIT, int ABF16>
__global__ __launch_bounds__(256) void gemm_bt(const void* __restrict__ Av, int lda,
                                               const float* __restrict__ W,
                                               float* __restrict__ C,
                                               int K, int N,
                                               const float* __restrict__ bias) {
    constexpr int BN = NR * 32;
    __shared__ unsigned short As[128][32];
    __shared__ unsigned short Ws[BN][32];
    const int tid = threadIdx.x;
    const int lane = tid & 63;
    const int wave = tid >> 6;
    const int wr = wave >> 1, wc = wave & 1;
    const int m0 = blockIdx.y * 128;
    const int n0 = blockIdx.x * BN;
    if (EPI == 3) {
        size_t z = blockIdx.z;
        W += z * (size_t)N * K;
        C += z * (size_t)1024 * N;
        bias += z * N;
    }
    f32x4 acc[4][NR];
#pragma unroll
    for (int m = 0; m < 4; ++m)
#pragma unroll
        for (int n = 0; n < NR; ++n) acc[m][n] = (f32x4)0.f;

    const int lr = lane & 15;
    const int lk = (lane >> 4) << 3;

    const int kc = (KSPLIT > 1) ? blockIdx.z : 0;
    const int Kc = K / KSPLIT;
    for (int k0 = kc * Kc; k0 < (kc + 1) * Kc; k0 += 32) {
        __syncthreads();
        if (ABF16) {
            const unsigned short* Ab = (const unsigned short*)Av;
#pragma unroll
            for (int i = 0; i < 2; ++i) {       // 128x32 bf16 = 512 x 16B
                int unit = tid + i * 256;
                int row = unit >> 2, c8 = (unit & 3) << 3;
                *(f32x4*)&As[row][c8] =
                    *(const f32x4*)&Ab[(size_t)(m0 + row) * lda + k0 + c8];
            }
        } else {
            const float* Af = (const float*)Av;
#pragma unroll
            for (int i = 0; i < 4; ++i) {
                int idx = tid + i * 256;
                int row = idx >> 3, c4 = (idx & 7) << 2;
                f32x4 v = *(const f32x4*)&Af[(size_t)(m0 + row) * lda + k0 + c4];
                unsigned long long pk = (unsigned long long)f2bf(v[0])
                                      | ((unsigned long long)f2bf(v[1]) << 16)
                                      | ((unsigned long long)f2bf(v[2]) << 32)
                                      | ((unsigned long long)f2bf(v[3]) << 48);
                *(unsigned long long*)&As[row][c4] = pk;
            }
        }
#pragma unroll
        for (int i = 0; i < NR; ++i) {          // stage W: BN x 32 fp32 -> bf16
            int idx = tid + i * 256;
            int row = idx >> 3, c4 = (idx & 7) << 2;
            f32x4 v = *(const f32x4*)&W[(size_t)(n0 + row) * K + k0 + c4];
            unsigned long long pk = (unsigned long long)f2bf(v[0])
                                  | ((unsigned long long)f2bf(v[1]) << 16)
                                  | ((unsigned long long)f2bf(v[2]) << 32)
                                  | ((unsigned long long)f2bf(v[3]) << 48);
            *(unsigned long long*)&Ws[row][c4] = pk;
        }
        __syncthreads();
        bf16x8 af[4], wf[NR];
#pragma unroll
        for (int m = 0; m < 4; ++m)
            af[m] = *(const bf16x8*)&As[wr * 64 + m * 16 + lr][lk];
#pragma unroll
        for (int n = 0; n < NR; ++n)
            wf[n] = *(const bf16x8*)&Ws[wc * (NR * 16) + n * 16 + lr][lk];
#pragma unroll
        for (int m = 0; m < 4; ++m)
#pragma unroll
            for (int n = 0; n < NR; ++n)
                acc[m][n] = __builtin_amdgcn_mfma_f32_16x16x32_bf16(af[m], wf[n], acc[m][n], 0, 0, 0);
    }

    const int mo = m0 + wr * 64;
    const int no = n0 + wc * (NR * 16);
    const int rbase = (lane >> 4) << 2;
#pragma unroll
    for (int m = 0; m < 4; ++m) {
#pragma unroll
        for (int n = 0; n < NR; ++n) {
            int col = no + n * 16 + lr;
#pragma unroll
            for (int j = 0; j < 4; ++j) {
                int row = mo + m * 16 + rbase + j;
                float v = acc[m][n][j];
                if (EPI == 2) {
                    atomicAdd(&C[(size_t)row * N + col], v);
                } else {
                    if (EPI == 1) v = fsoftplus(v + bias[col]);
                    else if (EPI == 3) v += bias[col];
                    C[(size_t)row * N + col] = v;
                }
            }
        }
    }
}

extern "C" void kernel_launch(void* const* d_in, const int* in_sizes, int n_in,
                              void* d_out, int out_size, void* d_ws, size_t ws_size,
                              hipStream_t stream) {
    const int*   seq     = (const int*)d_in[0];
    const float* embW    = (const float*)d_in[1];
    const float* norm_w  = (const float*)d_in[2];
    const float* in_W    = (const float*)d_in[3];
    const float* conv_w  = (const float*)d_in[4];
    const float* conv_b  = (const float*)d_in[5];
    const float* x_W     = (const float*)d_in[6];
    const float* dt_W    = (const float*)d_in[7];
    const float* dt_b    = (const float*)d_in[8];
    const float* A_log   = (const float*)d_in[9];
    const float* D_skip  = (const float*)d_in[10];
    const float* out_W   = (const float*)d_in[11];
    const float* normf_w = (const float*)d_in[12];
    const float* head_W  = (const float*)d_in[13];
    const float* head_b  = (const float*)d_in[14];

    float* ws   = (float*)d_ws;
    float* x    = ws;                                  // S*D f32
    float* proj = x    + (size_t)S * D;                // S*4096 f32
    float* u    = proj + (size_t)S * 4096;             // S*DI f32
    float* ssm  = u    + (size_t)S * DI;               // S*96 f32
    float* dtv  = ssm  + (size_t)S * 128;              // S*DI f32
    unsigned short* hnb = (unsigned short*)(dtv + (size_t)S * DI);  // S*D bf16
    unsigned short* ub  = hnb + (size_t)S * D;                      // S*DI bf16
    unsigned short* yfb = ub  + (size_t)S * DI;                     // S*DI bf16

    embed_kernel<<<S, 256, 0, stream>>>(seq, embW, x);

    for (int l = 0; l < NL; ++l) {
        rmsnorm_kernel<<<S, 256, 0, stream>>>(x, norm_w + (size_t)l * D, hnb);
        gemm_bt<4, 0, 1, 1><<<dim3(32, 8), 256, 0, stream>>>(hnb, D,
            in_W + (size_t)l * 4096 * D, proj, D, 4096, nullptr);
        conv_silu_kernel<<<(S * DI) / 256, 256, 0, stream>>>(proj,
            conv_w + (size_t)l * DI * 4, conv_b + (size_t)l * DI, u, ub, ssm);
        gemm_bt<3, 2, 8, 1><<<dim3(1, 8, 8), 256, 0, stream>>>(ub, DI,
            x_W + (size_t)l * XPD * DI, ssm, DI, XPD, nullptr);
        gemm_bt<4, 1, 1, 0><<<dim3(16, 8), 256, 0, stream>>>(ssm, XPD,
            dt_W + (size_t)l * DI * DTR, dtv, DTR, DI, dt_b + (size_t)l * DI);
        scan2_kernel<<<DI / 4, 1024, 0, stream>>>(dtv, u, ssm, proj,
            A_log + (size_t)l * DI * NSTATE, D_skip + (size_t)l * DI, yfb);
        gemm_bt<4, 2, 4, 1><<<dim3(8, 8, 4), 256, 0, stream>>>(yfb, DI,
            out_W + (size_t)l * D * DI, x, DI, D, nullptr);
    }

    rmsnorm_kernel<<<S, 256, 0, stream>>>(x, normf_w, hnb);
    gemm_bt<4, 3, 1, 1><<<dim3(16, 8, 4), 256, 0, stream>>>(hnb, D,
        head_W, (float*)d_out, D, CARD, head_b);
}

// Round 3
// 8435.262 us; speedup vs baseline: 6.3530x; 1.1930x over previous
//
#include <hip/hip_runtime.h>
#include <hip/hip_bf16.h>

#define S 1024
#define D 1024
#define DI 2048
#define NSTATE 16
#define DTR 64
#define XPD 96      // DT_RANK + 2N
#define NL 48
#define CARD 2048
#define KTOK 4

typedef __attribute__((ext_vector_type(8))) short bf16x8;
typedef __attribute__((ext_vector_type(4))) float f32x4;
struct __align__(16) US8 { unsigned long long a, b; };

__device__ __forceinline__ unsigned short f2bf(float f) {
    unsigned u = __builtin_bit_cast(unsigned, f);
    return (unsigned short)((u + 0x7fffu + ((u >> 16) & 1u)) >> 16);
}
__device__ __forceinline__ float bf2f(unsigned short u) {
    return __builtin_bit_cast(float, (unsigned)u << 16);
}
__device__ __forceinline__ float fsilu(float x) { return x / (1.f + __expf(-x)); }
__device__ __forceinline__ float fsoftplus(float x) {
    return fmaxf(x, 0.f) + log1pf(__expf(-fabsf(x)));
}
template<int CTRL>
__device__ __forceinline__ float dpp_add(float v) {
    int m = __builtin_amdgcn_update_dpp(0, __builtin_bit_cast(int, v), CTRL, 0xF, 0xF, true);
    return v + __builtin_bit_cast(float, m);
}
__device__ __forceinline__ void gload_lds16(const void* g, void* l) {
    __builtin_amdgcn_global_load_lds((const __attribute__((address_space(1))) void*)g,
                                     (__attribute__((address_space(3))) void*)l, 16, 0, 0);
}

// ---------------- fp32 -> bf16 weight convert (4 arrays, sizes in 8-elem units) ----------------
template<int NA, int NB, int NC, int ND>
__global__ __launch_bounds__(256) void cvt4_kernel(const float* __restrict__ a,
                                                   const float* __restrict__ b,
                                                   const float* __restrict__ c,
                                                   const float* __restrict__ d,
                                                   unsigned short* __restrict__ oa,
                                                   unsigned short* __restrict__ ob,
                                                   unsigned short* __restrict__ oc,
                                                   unsigned short* __restrict__ od) {
    int i = blockIdx.x * 256 + threadIdx.x;
    const float* src; unsigned short* dst; int off;
    if (i < NA)                    { src = a; dst = oa; off = i; }
    else if (i < NA + NB)          { src = b; dst = ob; off = i - NA; }
    else if (i < NA + NB + NC)     { src = c; dst = oc; off = i - NA - NB; }
    else                            { src = d; dst = od; off = i - NA - NB - NC; }
    f32x4 v0 = *(const f32x4*)&src[(size_t)off * 8];
    f32x4 v1 = *(const f32x4*)&src[(size_t)off * 8 + 4];
    US8 pk;
    pk.a = (unsigned long long)f2bf(v0[0]) | ((unsigned long long)f2bf(v0[1]) << 16)
         | ((unsigned long long)f2bf(v0[2]) << 32) | ((unsigned long long)f2bf(v0[3]) << 48);
    pk.b = (unsigned long long)f2bf(v1[0]) | ((unsigned long long)f2bf(v1[1]) << 16)
         | ((unsigned long long)f2bf(v1[2]) << 32) | ((unsigned long long)f2bf(v1[3]) << 48);
    *(US8*)&dst[(size_t)off * 8] = pk;
}

// ---------------- embedding: x[s][d] = sum_k emb_W[k][seq[k][s]][d] ----------------
__global__ __launch_bounds__(256) void embed_kernel(const int* __restrict__ seq,
                                                    const float* __restrict__ embW,
                                                    float* __restrict__ x) {
    int s = blockIdx.x, t = threadIdx.x;
    f32x4 acc = (f32x4)0.f;
#pragma unroll
    for (int k = 0; k < KTOK; ++k) {
        int tok = seq[k * S + s];
        const f32x4 v = *(const f32x4*)&embW[((size_t)k * CARD + tok) * D + t * 4];
        acc += v;
    }
    *(f32x4*)&x[(size_t)s * D + t * 4] = acc;
}

// ---------------- RMSNorm over rows of length D, bf16 output ----------------
__global__ __launch_bounds__(256) void rmsnorm_kernel(const float* __restrict__ x,
                                                      const float* __restrict__ w,
                                                      unsigned short* __restrict__ o) {
    int row = blockIdx.x, t = threadIdx.x;
    f32x4 v = *(const f32x4*)&x[(size_t)row * D + t * 4];
    float ss = v[0]*v[0] + v[1]*v[1] + v[2]*v[2] + v[3]*v[3];
#pragma unroll
    for (int off = 32; off >= 1; off >>= 1) ss += __shfl_xor(ss, off);
    __shared__ float red[4];
    int wave = t >> 6, lane = t & 63;
    if (lane == 0) red[wave] = ss;
    __syncthreads();
    ss = red[0] + red[1] + red[2] + red[3];
    float rs = rsqrtf(ss * (1.f / D) + 1e-5f);
    f32x4 wv = *(const f32x4*)&w[t * 4];
    unsigned long long pk = 0;
#pragma unroll
    for (int j = 0; j < 4; ++j)
        pk |= (unsigned long long)f2bf(v[j] * rs * wv[j]) << (16 * j);
    *(unsigned long long*)&o[(size_t)row * D + t * 4] = pk;
}

// ---------- causal depthwise conv1d (k=4) + bias + silu (bf16 out); zeroes ssm ----------
__global__ __launch_bounds__(256) void conv_silu_kernel(const float* __restrict__ proj,
                                                        const float* __restrict__ cw,
                                                        const float* __restrict__ cb,
                                                        unsigned short* __restrict__ ub,
                                                        float* __restrict__ ssm_zero) {
    int idx = blockIdx.x * 256 + threadIdx.x;   // s*DI + c
    if (blockIdx.x < (S * XPD) / 256)           // 384 blocks zero ssm (1024*96)
        ssm_zero[idx] = 0.f;
    int s = idx >> 11, c = idx & (DI - 1);
    f32x4 w = *(const f32x4*)&cw[c * 4];
    float acc = cb[c];
#pragma unroll
    for (int t = 0; t < 4; ++t) {
        int ss = s - 3 + t;
        if (ss >= 0) acc = fmaf(w[t], proj[(size_t)ss * 4096 + c], acc);
    }
    ub[idx] = f2bf(acc * (1.f / (1.f + __expf(-acc))));
}

// ---------------- chunked selective scan (2-phase, DPP reduction) ----------------
// block: 1024 thr = 16 chunks x 4 d x 16 n; grid = DI/4 = 512 blocks. LDS 40KB.
__global__ __launch_bounds__(1024, 2) void scan2_kernel(const float* __restrict__ dt,
                                                        const unsigned short* __restrict__ ub,
                                                        const float* __restrict__ ssm,
                                                        const float* __restrict__ proj,
                                                        const float* __restrict__ A_log,
                                                        const float* __restrict__ Dsk,
                                                        unsigned short* __restrict__ yfb) {
    __shared__ float sdt[S * 4];      // [s][dl]
    __shared__ float su[S * 4];
    __shared__ float sP[1024], sQ[1024];

    const int tid = threadIdx.x;
    const int d0 = blockIdx.x * 4;
    const int chunk = tid >> 6;       // 16 chunks of 64 steps
    const int dl = (tid >> 4) & 3;
    const int n = tid & 15;

#pragma unroll
    for (int i = 0; i < 4; ++i) {
        int idx = tid + i * 1024;
        int s = idx >> 2, d2 = idx & 3;
        sdt[idx] = dt[(size_t)s * DI + d0 + d2];
        su[idx]  = bf2f(ub[(size_t)s * DI + d0 + d2]);
    }
    const float Av = -__expf(A_log[(d0 + dl) * NSTATE + n]);
    const float Dv = Dsk[d0 + dl];
    __syncthreads();

    const int sbase = chunk * 64;
    // pass A: local scan from zero + product of dA
    float h = 0.f, P = 1.f;
#pragma unroll 4
    for (int i = 0; i < 64; ++i) {
        int s = sbase + i;
        float dts = sdt[s * 4 + dl];
        float us  = su[s * 4 + dl];
        float Bs  = ssm[s * XPD + DTR + n];
        float dA  = __expf(dts * Av);
        P *= dA;
        h = fmaf(dA, h, dts * us * Bs);
    }
    const int pqb = (dl * 16 + n) * 16;
    sP[pqb + chunk] = P;
    sQ[pqb + chunk] = h;
    __syncthreads();
    float hi = 0.f;
    for (int j = 0; j < chunk; ++j) hi = fmaf(sP[pqb + j], hi, sQ[pqb + j]);
    // pass B: true scan, DPP tree-sum over 16 n-lanes, direct global out
    h = hi;
#pragma unroll 2
    for (int i = 0; i < 64; ++i) {
        int s = sbase + i;
        float dts = sdt[s * 4 + dl];
        float us  = su[s * 4 + dl];
        float Bs  = ssm[s * XPD + DTR + n];
        float Cs  = ssm[s * XPD + DTR + NSTATE + n];
        float dA  = __expf(dts * Av);
        h = fmaf(dA, h, dts * us * Bs);
        float pc = h * Cs;
        pc = dpp_add<0xB1>(pc);    // quad_perm xor1
        pc = dpp_add<0x4E>(pc);    // quad_perm xor2
        pc = dpp_add<0x124>(pc);   // row_ror:4
        pc = dpp_add<0x128>(pc);   // row_ror:8 -> full 16-lane sum
        if (n == 0) {
            float g = proj[(size_t)s * 4096 + 2048 + d0 + dl];
            yfb[(size_t)s * DI + d0 + dl] = f2bf((pc + us * Dv) * fsilu(g));
        }
    }
}

// ---------------- GEMM: C(1024 x N) = A(1024 x K, lda) * Wb(N x K)^T, W bf16 ----------------
// bf16 MFMA 16x16x32, 128 x (NR*32) tile, 4 waves (2x2), global_load_lds staging.
// EPI: 0 store, 1 softplus(acc+bias), 2 atomicAdd (split-K/residual), 3 bias+store z-batched
// ABF16: A bf16 (gload_lds) else fp32 (reg-stage + convert)
template<int NR, int EPI, int KSPLIT, int ABF16>
__global__ __launch_bounds__(256) void gemm_bt(const void* __restrict__ Av, int lda,
                                               const unsigned short* __restrict__ W,
                                               float* __restrict__ C,
                                               int K, int N,
                                               const float* __restrict__ bias) {
    constexpr int BN = NR * 32;
    __shared__ unsigned short As[128][32];
    __shared__ unsigned short Ws[BN][32];
    const int tid = threadIdx.x;
    const int lane = tid & 63;
    const int wave = tid >> 6;
    const int wr = wave >> 1, wc = wave & 1;
    const int m0 = blockIdx.y * 128;
    const int n0 = blockIdx.x * BN;
    const unsigned short* Wp = W;
    const float* biasp = bias;
    float* Cp = C;
    if (EPI == 3) {
        size_t z = blockIdx.z;
        Wp += z * (size_t)N * K;
        Cp += z * (size_t)1024 * N;
        biasp += z * N;
    }
    f32x4 acc[4][NR];
#pragma unroll
    for (int m = 0; m < 4; ++m)
#pragma unroll
        for (int n = 0; n < NR; ++n) acc[m][n] = (f32x4)0.f;

    const int lr = lane & 15;
    const int lk = (lane >> 4) << 3;
    const int grow = lane >> 2;          // gload: row within 16-row unit
    const int gcol = (lane & 3) << 3;    // gload: bf16 col offset

    const int kc = (KSPLIT > 1) ? blockIdx.z : 0;
    const int Kc = K / KSPLIT;
    for (int k0 = kc * Kc; k0 < (kc + 1) * Kc; k0 += 32) {
        __syncthreads();
        if (ABF16) {
            const unsigned short* Ab = (const unsigned short*)Av;
#pragma unroll
            for (int u2 = wave; u2 < 8; u2 += 4)
                gload_lds16(&Ab[(size_t)(m0 + u2 * 16 + grow) * lda + k0 + gcol],
                            &As[u2 * 16][0]);
        } else {
            const float* Af = (const float*)Av;
#pragma unroll
            for (int i = 0; i < 4; ++i) {
                int idx = tid + i * 256;
                int row = idx >> 3, c4 = (idx & 7) << 2;
                f32x4 v = *(const f32x4*)&Af[(size_t)(m0 + row) * lda + k0 + c4];
                unsigned long long pk = (unsigned long long)f2bf(v[0])
                                      | ((unsigned long long)f2bf(v[1]) << 16)
                                      | ((unsigned long long)f2bf(v[2]) << 32)
                                      | ((unsigned long long)f2bf(v[3]) << 48);
                *(unsigned long long*)&As[row][c4] = pk;
            }
        }
#pragma unroll
        for (int u2 = wave; u2 < BN / 16; u2 += 4)
            gload_lds16(&Wp[(size_t)(n0 + u2 * 16 + grow) * K + k0 + gcol],
                        &Ws[u2 * 16][0]);
        __syncthreads();
        bf16x8 af[4], wf[NR];
#pragma unroll
        for (int m = 0; m < 4; ++m)
            af[m] = *(const bf16x8*)&As[wr * 64 + m * 16 + lr][lk];
#pragma unroll
        for (int n = 0; n < NR; ++n)
            wf[n] = *(const bf16x8*)&Ws[wc * (NR * 16) + n * 16 + lr][lk];
#pragma unroll
        for (int m = 0; m < 4; ++m)
#pragma unroll
            for (int n = 0; n < NR; ++n)
                acc[m][n] = __builtin_amdgcn_mfma_f32_16x16x32_bf16(af[m], wf[n], acc[m][n], 0, 0, 0);
    }

    const int mo = m0 + wr * 64;
    const int no = n0 + wc * (NR * 16);
    const int rbase = (lane >> 4) << 2;
#pragma unroll
    for (int m = 0; m < 4; ++m) {
#pragma unroll
        for (int n = 0; n < NR; ++n) {
            int col = no + n * 16 + lr;
#pragma unroll
            for (int j = 0; j < 4; ++j) {
                int row = mo + m * 16 + rbase + j;
                float v = acc[m][n][j];
                if (EPI == 2) {
                    atomicAdd(&Cp[(size_t)row * N + col], v);
                } else {
                    if (EPI == 1) v = fsoftplus(v + biasp[col]);
                    else if (EPI == 3) v += biasp[col];
                    Cp[(size_t)row * N + col] = v;
                }
            }
        }
    }
}

// sizes in 8-elem units
#define IN_U  (4096 * 1024 / 8)
#define OUT_U (1024 * 2048 / 8)
#define X_U   (XPD * 2048 / 8)
#define DT_U  (2048 * 64 / 8)
#define HEAD_U (KTOK * CARD * 1024 / 8)

extern "C" void kernel_launch(void* const* d_in, const int* in_sizes, int n_in,
                              void* d_out, int out_size, void* d_ws, size_t ws_size,
                              hipStream_t stream) {
    const int*   seq     = (const int*)d_in[0];
    const float* embW    = (const float*)d_in[1];
    const float* norm_w  = (const float*)d_in[2];
    const float* in_W    = (const float*)d_in[3];
    const float* conv_w  = (const float*)d_in[4];
    const float* conv_b  = (const float*)d_in[5];
    const float* x_W     = (const float*)d_in[6];
    const float* dt_W    = (const float*)d_in[7];
    const float* dt_b    = (const float*)d_in[8];
    const float* A_log   = (const float*)d_in[9];
    const float* D_skip  = (const float*)d_in[10];
    const float* out_W   = (const float*)d_in[11];
    const float* normf_w = (const float*)d_in[12];
    const float* head_W  = (const float*)d_in[13];
    const float* head_b  = (const float*)d_in[14];

    float* ws   = (float*)d_ws;
    float* x    = ws;                                  // S*D f32          4MB
    float* proj = x    + (size_t)S * D;                // S*4096 f32      16MB
    float* ssm  = proj + (size_t)S * 4096;             // S*96 (pad 128)   0.5MB
    float* dtv  = ssm  + (size_t)S * 128;              // S*DI f32         8MB
    unsigned short* hnb = (unsigned short*)(dtv + (size_t)S * DI);  // S*D bf16   2MB
    unsigned short* ub  = hnb + (size_t)S * D;                      // S*DI bf16  4MB
    unsigned short* yfb = ub  + (size_t)S * DI;                     // S*DI bf16  4MB
    unsigned short* inWb  = yfb  + (size_t)S * DI;     // 4096*1024 bf16   8.4MB
    unsigned short* outWb = inWb + (size_t)4096 * D;   // 1024*2048 bf16   4.2MB
    unsigned short* xWb   = outWb + (size_t)D * DI;    // 96*2048 bf16     0.4MB
    unsigned short* dtWb  = xWb  + (size_t)XPD * DI;   // 2048*64 bf16     0.26MB
    unsigned short* headWb = dtWb + (size_t)DI * DTR;  // 4*2048*1024 bf16 16.8MB

    embed_kernel<<<S, 256, 0, stream>>>(seq, embW, x);
    cvt4_kernel<HEAD_U, 0, 0, 0><<<HEAD_U / 256, 256, 0, stream>>>(
        head_W, nullptr, nullptr, nullptr, headWb, nullptr, nullptr, nullptr);

    for (int l = 0; l < NL; ++l) {
        cvt4_kernel<IN_U, OUT_U, X_U, DT_U><<<(IN_U + OUT_U + X_U + DT_U) / 256, 256, 0, stream>>>(
            in_W + (size_t)l * 4096 * D, out_W + (size_t)l * D * DI,
            x_W + (size_t)l * XPD * DI, dt_W + (size_t)l * DI * DTR,
            inWb, outWb, xWb, dtWb);
        rmsnorm_kernel<<<S, 256, 0, stream>>>(x, norm_w + (size_t)l * D, hnb);
        gemm_bt<4, 0, 1, 1><<<dim3(32, 8), 256, 0, stream>>>(hnb, D, inWb,
            proj, D, 4096, nullptr);
        conv_silu_kernel<<<(S * DI) / 256, 256, 0, stream>>>(proj,
            conv_w + (size_t)l * DI * 4, conv_b + (size_t)l * DI, ub, ssm);
        gemm_bt<3, 2, 16, 1><<<dim3(1, 8, 16), 256, 0, stream>>>(ub, DI, xWb,
            ssm, DI, XPD, nullptr);
        gemm_bt<4, 1, 1, 0><<<dim3(16, 8), 256, 0, stream>>>(ssm, XPD, dtWb,
            dtv, DTR, DI, dt_b + (size_t)l * DI);
        scan2_kernel<<<DI / 4, 1024, 0, stream>>>(dtv, ub, ssm, proj,
            A_log + (size_t)l * DI * NSTATE, D_skip + (size_t)l * DI, yfb);
        gemm_bt<4, 2, 4, 1><<<dim3(8, 8, 4), 256, 0, stream>>>(yfb, DI, outWb,
            x, DI, D, nullptr);
    }

    rmsnorm_kernel<<<S, 256, 0, stream>>>(x, normf_w, hnb);
    gemm_bt<4, 3, 1, 1><<<dim3(16, 8, 4), 256, 0, stream>>>(hnb, D, headWb,
        (float*)d_out, D, CARD, head_b);
}